// Round 6
// baseline (1297.431 us; speedup 1.0000x reference)
//
#include <hip/hip_runtime.h>

#define NREL 3
#define EMB 32
#define HID 64
#define TILE 64

// ================= CSR build, RELATION-MAJOR: key = rel*N + dst =================
__global__ __launch_bounds__(256) void hist_k(const int* __restrict__ dst,
                                              const int* __restrict__ et,
                                              int* __restrict__ icnt, int E, int N) {
  int e = blockIdx.x * 256 + threadIdx.x;
  if (e >= E) return;
  atomicAdd(&icnt[et[e] * N + dst[e]], 1);
}

__global__ __launch_bounds__(256) void scan1_k(const int* __restrict__ icnt,
                                               int* __restrict__ psum, int M) {
  int base = blockIdx.x * 1024 + threadIdx.x * 4;
  int s = 0;
#pragma unroll
  for (int j = 0; j < 4; j++) {
    int i = base + j;
    if (i < M) s += icnt[i];
  }
  __shared__ int tmp[256];
  tmp[threadIdx.x] = s;
  __syncthreads();
  for (int off = 128; off > 0; off >>= 1) {
    if (threadIdx.x < off) tmp[threadIdx.x] += tmp[threadIdx.x + off];
    __syncthreads();
  }
  if (threadIdx.x == 0) psum[blockIdx.x] = tmp[0];
}

__global__ __launch_bounds__(256) void scan2_k(int* __restrict__ psum, int P) {
  __shared__ int tmp[256];
  __shared__ int carry_s;
  if (threadIdx.x == 0) carry_s = 0;
  __syncthreads();
  for (int base = 0; base < P; base += 256) {
    int i = base + threadIdx.x;
    int v = (i < P) ? psum[i] : 0;
    tmp[threadIdx.x] = v;
    __syncthreads();
    for (int off = 1; off < 256; off <<= 1) {
      int u = (threadIdx.x >= off) ? tmp[threadIdx.x - off] : 0;
      __syncthreads();
      tmp[threadIdx.x] += u;
      __syncthreads();
    }
    int carry = carry_s;
    if (i < P) psum[i] = carry + tmp[threadIdx.x] - v;
    __syncthreads();
    if (threadIdx.x == 0) carry_s = carry + tmp[255];
    __syncthreads();
  }
}

__global__ __launch_bounds__(256) void scan3_k(const int* __restrict__ icnt,
                                               const int* __restrict__ psum,
                                               int* __restrict__ offs, int M) {
  int base = blockIdx.x * 1024 + threadIdx.x * 4;
  int v[4];
  int s = 0;
#pragma unroll
  for (int j = 0; j < 4; j++) {
    int i = base + j;
    v[j] = (i < M) ? icnt[i] : 0;
    s += v[j];
  }
  __shared__ int tmp[256];
  tmp[threadIdx.x] = s;
  __syncthreads();
  for (int off = 1; off < 256; off <<= 1) {
    int u = (threadIdx.x >= off) ? tmp[threadIdx.x - off] : 0;
    __syncthreads();
    tmp[threadIdx.x] += u;
    __syncthreads();
  }
  int run = psum[blockIdx.x] + tmp[threadIdx.x] - s;
#pragma unroll
  for (int j = 0; j < 4; j++) {
    int i = base + j;
    if (i < M) {
      offs[i] = run;
      run += v[j];
    }
  }
}

__global__ __launch_bounds__(256) void scatter_k(const int* __restrict__ src,
                                                 const int* __restrict__ dst,
                                                 const int* __restrict__ et,
                                                 int* __restrict__ cursor,
                                                 int* __restrict__ csr,
                                                 int* __restrict__ dtag, int E, int N) {
  int e = blockIdx.x * 256 + threadIdx.x;
  if (e >= E) return;
  int d = dst[e];
  int p = atomicAdd(&cursor[et[e] * N + d], 1);
  csr[p] = src[e];
  dtag[p] = d;
}

// ====== layer-1 fused: edge-parallel LDS-atomic agg (embeddings) + tiled GEMM -> h1 ======
__global__ __launch_bounds__(256) void l1fused_k(
    const int* __restrict__ sid, const int* __restrict__ cid, const int* __restrict__ pid,
    const float* __restrict__ se, const float* __restrict__ ce, const float* __restrict__ pe,
    const int* __restrict__ offs, const int* __restrict__ icnt,
    const int* __restrict__ csr, const int* __restrict__ dtag,
    const float* __restrict__ root, const float* __restrict__ W, const float* __restrict__ bias,
    float* __restrict__ h1, int N, int E) {
  __shared__ float As[TILE][132];  // [x | m0 | m1 | m2], row stride 528 B (16B mult)
  __shared__ float Ws[64][64];
  const int t = threadIdx.x;
  const int tx = t & 15, ty = t >> 4;
  const int lane = t & 63, wave = t >> 6;
  const int n0 = blockIdx.x * TILE;
  const int nend = (n0 + TILE < N) ? n0 + TILE : N;

  // zero whole A tile
  for (int i = t; i < TILE * 132; i += 256) ((float*)As)[i] = 0.f;
  __syncthreads();

  // self segment: x rows from embedding tables
  {
    int rr = t >> 5, col = t & 31;
#pragma unroll
    for (int i = 0; i < 8; i++) {
      int row = rr * 8 + i;
      int n = n0 + row;
      if (n >= N) n = N - 1;
      As[row][col] = se[sid[n] * EMB + col] + ce[cid[n] * EMB + col] + pe[pid[n] * EMB + col];
    }
  }
  // 3 relation segments: edge-parallel walk, 2 edges/wave-iter (32-lane halves)
  {
    int h = lane >> 5, col = lane & 31;
    for (int r = 0; r < NREL; r++) {
      int idx0 = r * N + n0;
      int idx1 = r * N + nend;
      int beg = offs[idx0];
      int end = (idx1 < NREL * N) ? offs[idx1] : E;
      for (int e = beg + wave * 2 + h; e < end; e += 8) {
        int s = csr[e];
        int row = dtag[e] - n0;
        float v = se[sid[s] * EMB + col] + ce[cid[s] * EMB + col] + pe[pid[s] * EMB + col];
        atomicAdd(&As[row][32 + r * 32 + col], v);
      }
    }
  }
  __syncthreads();
  // normalize means: 192 (row, r) pairs
  if (t < 192) {
    int row = t / 3, r = t - row * 3;
    int n = n0 + row;
    if (n >= N) n = N - 1;
    float inv = 1.0f / fmaxf((float)icnt[r * N + n], 1.f);
#pragma unroll
    for (int c = 0; c < 32; c += 4) {
      float4 v = *(float4*)&As[row][32 + r * 32 + c];
      v.x *= inv; v.y *= inv; v.z *= inv; v.w *= inv;
      *(float4*)&As[row][32 + r * 32 + c] = v;
    }
  }

  // GEMM: K = 128 in 2 chunks of 64
  float acc[4][4] = {};
  for (int kc = 0; kc < 2; kc++) {
    __syncthreads();
#pragma unroll
    for (int p = 0; p < 4; p++) {
      int row = p * 16 + ty;
      int c4 = tx * 4;
      int wk = kc * 64 + row;
      float4 wv = (wk < EMB) ? *(const float4*)&root[wk * HID + c4]
                             : *(const float4*)&W[(wk - EMB) * HID + c4];
      *(float4*)&Ws[row][c4] = wv;
    }
    __syncthreads();
#pragma unroll 4
    for (int kq = 0; kq < 16; kq++) {
      float4 av[4], wv[4];
#pragma unroll
      for (int m = 0; m < 4; m++) av[m] = *(const float4*)&As[ty * 4 + m][kc * 64 + kq * 4];
#pragma unroll
      for (int i = 0; i < 4; i++) wv[i] = *(const float4*)&Ws[kq * 4 + i][tx * 4];
#pragma unroll
      for (int m = 0; m < 4; m++) {
        const float am[4] = {av[m].x, av[m].y, av[m].z, av[m].w};
#pragma unroll
        for (int i = 0; i < 4; i++) {
          acc[m][0] += am[i] * wv[i].x;
          acc[m][1] += am[i] * wv[i].y;
          acc[m][2] += am[i] * wv[i].z;
          acc[m][3] += am[i] * wv[i].w;
        }
      }
    }
  }
  const int c4 = tx * 4;
  const float4 bv = *(const float4*)&bias[c4];
#pragma unroll
  for (int m = 0; m < 4; m++) {
    int n = n0 + ty * 4 + m;
    if (n < N) {
      float4 o;
      o.x = fmaxf(acc[m][0] + bv.x, 0.f);
      o.y = fmaxf(acc[m][1] + bv.y, 0.f);
      o.z = fmaxf(acc[m][2] + bv.z, 0.f);
      o.w = fmaxf(acc[m][3] + bv.w, 0.f);
      *(float4*)&h1[(size_t)n * HID + c4] = o;
    }
  }
}

// ====== layer-2 fused: edge-parallel LDS-atomic agg (h1) per K-chunk + GEMM + pooled epilogue ======
__global__ __launch_bounds__(256) void l2fused_k(
    const float* __restrict__ h1,
    const int* __restrict__ offs, const int* __restrict__ icnt,
    const int* __restrict__ csr, const int* __restrict__ dtag,
    const float* __restrict__ root, const float* __restrict__ W, const float* __restrict__ bias,
    const float* __restrict__ linW, const int* __restrict__ batch,
    float* __restrict__ gs, float* __restrict__ gc, int N, int E) {
  __shared__ float As[TILE][68];
  __shared__ float Ws[64][64];
  const int t = threadIdx.x;
  const int tx = t & 15, ty = t >> 4;
  const int lane = t & 63, wave = t >> 6;
  const int n0 = blockIdx.x * TILE;
  const int nend = (n0 + TILE < N) ? n0 + TILE : N;
  float acc[4][4] = {};

  for (int kc = 0; kc < 4; kc++) {
    __syncthreads();  // protect As from previous chunk's GEMM reads
    if (kc == 0) {  // self: copy h1 rows
#pragma unroll
      for (int p = 0; p < 4; p++) {
        int row = p * 16 + ty;
        int c4 = tx * 4;
        int n = n0 + row;
        if (n >= N) n = N - 1;
        *(float4*)&As[row][c4] = *(const float4*)&h1[(size_t)n * HID + c4];
      }
    } else {  // relation kc-1: edge-parallel gather + LDS atomics
      int r = kc - 1;
      for (int i = t; i < TILE * HID; i += 256) As[i >> 6][i & 63] = 0.f;
      __syncthreads();
      int idx0 = r * N + n0;
      int idx1 = r * N + nend;
      int beg = offs[idx0];
      int end = (idx1 < NREL * N) ? offs[idx1] : E;
      int h = lane >> 5, c2 = (lane & 31) * 2;
      for (int e = beg + wave * 2 + h; e < end; e += 8) {
        int s = csr[e];
        int row = dtag[e] - n0;
        float2 v = *(const float2*)&h1[(size_t)s * HID + c2];
        atomicAdd(&As[row][c2], v.x);
        atomicAdd(&As[row][c2 + 1], v.y);
      }
      __syncthreads();
      // normalize: each wave 16 rows, 64 lanes cover 64 cols
      for (int i = 0; i < 16; i++) {
        int row = wave * 16 + i;
        int n = n0 + row;
        if (n >= N) n = N - 1;
        float inv = 1.0f / fmaxf((float)icnt[r * N + n], 1.f);
        As[row][lane] *= inv;
      }
    }
#pragma unroll
    for (int p = 0; p < 4; p++) {
      int row = p * 16 + ty;
      int c4 = tx * 4;
      int wk = kc * 64 + row;
      float4 wv = (wk < HID) ? *(const float4*)&root[wk * HID + c4]
                             : *(const float4*)&W[(wk - HID) * HID + c4];
      *(float4*)&Ws[row][c4] = wv;
    }
    __syncthreads();
#pragma unroll 4
    for (int kq = 0; kq < 16; kq++) {
      float4 av[4], wv[4];
#pragma unroll
      for (int m = 0; m < 4; m++) av[m] = *(const float4*)&As[ty * 4 + m][kq * 4];
#pragma unroll
      for (int i = 0; i < 4; i++) wv[i] = *(const float4*)&Ws[kq * 4 + i][tx * 4];
#pragma unroll
      for (int m = 0; m < 4; m++) {
        const float am[4] = {av[m].x, av[m].y, av[m].z, av[m].w};
#pragma unroll
        for (int i = 0; i < 4; i++) {
          acc[m][0] += am[i] * wv[i].x;
          acc[m][1] += am[i] * wv[i].y;
          acc[m][2] += am[i] * wv[i].z;
          acc[m][3] += am[i] * wv[i].w;
        }
      }
    }
  }
  // fused epilogue: bias+relu, project 64->2, reduce across 16 tx lanes, atomics
  const int c4 = tx * 4;
  const float4 bv = *(const float4*)&bias[c4];
  float lw0[4], lw1[4];
#pragma unroll
  for (int c = 0; c < 4; c++) {
    lw0[c] = linW[(c4 + c) * 2 + 0];
    lw1[c] = linW[(c4 + c) * 2 + 1];
  }
#pragma unroll
  for (int m = 0; m < 4; m++) {
    int n = n0 + ty * 4 + m;
    float v0 = fmaxf(acc[m][0] + bv.x, 0.f);
    float v1 = fmaxf(acc[m][1] + bv.y, 0.f);
    float v2 = fmaxf(acc[m][2] + bv.z, 0.f);
    float v3 = fmaxf(acc[m][3] + bv.w, 0.f);
    float t0 = v0 * lw0[0] + v1 * lw0[1] + v2 * lw0[2] + v3 * lw0[3];
    float t1 = v0 * lw1[0] + v1 * lw1[1] + v2 * lw1[2] + v3 * lw1[3];
#pragma unroll
    for (int o = 1; o < 16; o <<= 1) {
      t0 += __shfl_xor(t0, o, 16);
      t1 += __shfl_xor(t1, o, 16);
    }
    if (tx == 0 && n < N) {
      int g = batch[n];
      atomicAdd(&gs[g * 2 + 0], t0);
      atomicAdd(&gs[g * 2 + 1], t1);
      atomicAdd(&gc[g], 1.0f);
    }
  }
}

__global__ __launch_bounds__(256) void final_k(const float* __restrict__ gs,
                                               const float* __restrict__ gc,
                                               const float* __restrict__ linb,
                                               float* __restrict__ out, int G) {
  int i = blockIdx.x * 256 + threadIdx.x;
  if (i >= G * 2) return;
  int g = i >> 1, o = i & 1;
  out[i] = gs[i] / fmaxf(gc[g], 1.0f) + linb[o];
}

extern "C" void kernel_launch(void* const* d_in, const int* in_sizes, int n_in,
                              void* d_out, int out_size, void* d_ws, size_t ws_size,
                              hipStream_t stream) {
  const int* sid = (const int*)d_in[0];
  const int* cid = (const int*)d_in[1];
  const int* pid = (const int*)d_in[2];
  const int* ei = (const int*)d_in[3];
  const int* et = (const int*)d_in[4];
  const int* batch = (const int*)d_in[5];
  const float* se = (const float*)d_in[7];
  const float* ce = (const float*)d_in[8];
  const float* pe = (const float*)d_in[9];
  const float* W1 = (const float*)d_in[10];
  const float* root1 = (const float*)d_in[11];
  const float* b1 = (const float*)d_in[12];
  const float* W2 = (const float*)d_in[13];
  const float* root2 = (const float*)d_in[14];
  const float* b2 = (const float*)d_in[15];
  const float* linW = (const float*)d_in[16];
  const float* linb = (const float*)d_in[17];
  float* out = (float*)d_out;

  const int N = in_sizes[0];
  const int E = in_sizes[4];
  const int G = out_size / 2;
  const int* src = ei;
  const int* dst = ei + E;
  const int M = N * NREL;
  const int P = (M + 1023) / 1024;

  // ---- workspace layout (strictly budgeted) ----
  char* w = (char*)d_ws;
  float* h1 = (float*)w;      w += (size_t)N * HID * sizeof(float);
  float* gs = (float*)w;      w += (size_t)G * 2 * sizeof(float);
  float* gc = (float*)w;      w += (size_t)G * sizeof(float);
  int* icnt = (int*)w;        w += (size_t)M * sizeof(int);
  int* offs = (int*)w;        w += (size_t)M * sizeof(int);
  int* cursor = (int*)w;      w += (size_t)M * sizeof(int);
  int* csr = (int*)w;         w += (size_t)E * sizeof(int);
  int* dtag = (int*)w;        w += (size_t)E * sizeof(int);
  int* psum = (int*)w;        w += (size_t)P * sizeof(int);
  if ((size_t)(w - (char*)d_ws) > ws_size) return;  // ws too small: fail loudly, no OOB

  hipMemsetAsync(icnt, 0, (size_t)M * sizeof(int), stream);
  hipMemsetAsync(gs, 0, (size_t)G * 3 * sizeof(float), stream);

  hist_k<<<(E + 255) / 256, 256, 0, stream>>>(dst, et, icnt, E, N);
  scan1_k<<<P, 256, 0, stream>>>(icnt, psum, M);
  scan2_k<<<1, 256, 0, stream>>>(psum, P);
  scan3_k<<<P, 256, 0, stream>>>(icnt, psum, offs, M);
  hipMemcpyAsync(cursor, offs, (size_t)M * sizeof(int), hipMemcpyDeviceToDevice, stream);
  scatter_k<<<(E + 255) / 256, 256, 0, stream>>>(src, dst, et, cursor, csr, dtag, E, N);

  int blocks = (N + TILE - 1) / TILE;
  l1fused_k<<<blocks, 256, 0, stream>>>(sid, cid, pid, se, ce, pe, offs, icnt, csr, dtag, root1,
                                        W1, b1, h1, N, E);
  l2fused_k<<<blocks, 256, 0, stream>>>(h1, offs, icnt, csr, dtag, root2, W2, b2, linW, batch,
                                        gs, gc, N, E);
  final_k<<<(G * 2 + 255) / 256, 256, 0, stream>>>(gs, gc, linb, out, G);
}

// Round 7
// 650.370 us; speedup vs baseline: 1.9949x; 1.9949x over previous
//
#include <hip/hip_runtime.h>

#define NREL 3
#define EMB 32
#define HID 64
#define TILE 64

// ---------------- embedding materialize: x[n][0:32] ----------------
__global__ __launch_bounds__(256) void embed_k(
    const int* __restrict__ sid, const int* __restrict__ cid, const int* __restrict__ pid,
    const float* __restrict__ se, const float* __restrict__ ce, const float* __restrict__ pe,
    float* __restrict__ x, int N) {
  int i = blockIdx.x * 256 + threadIdx.x;  // one float4 per thread
  if (i >= N * 8) return;
  int n = i >> 3, cg = i & 7;
  const float4 a = *(const float4*)&se[sid[n] * EMB + cg * 4];
  const float4 b = *(const float4*)&ce[cid[n] * EMB + cg * 4];
  const float4 c = *(const float4*)&pe[pid[n] * EMB + cg * 4];
  float4 v;
  v.x = a.x + b.x + c.x; v.y = a.y + b.y + c.y;
  v.z = a.z + b.z + c.z; v.w = a.w + b.w + c.w;
  *(float4*)&x[(size_t)n * EMB + cg * 4] = v;
}

// ================= CSR build, RELATION-MAJOR: key = rel*N + dst =================
__global__ __launch_bounds__(256) void hist_k(const int* __restrict__ dst,
                                              const int* __restrict__ et,
                                              int* __restrict__ icnt, int E, int N) {
  int e = blockIdx.x * 256 + threadIdx.x;
  if (e >= E) return;
  atomicAdd(&icnt[et[e] * N + dst[e]], 1);
}

__global__ __launch_bounds__(256) void scan1_k(const int* __restrict__ icnt,
                                               int* __restrict__ psum, int M) {
  int base = blockIdx.x * 1024 + threadIdx.x * 4;
  int s = 0;
#pragma unroll
  for (int j = 0; j < 4; j++) {
    int i = base + j;
    if (i < M) s += icnt[i];
  }
  __shared__ int tmp[256];
  tmp[threadIdx.x] = s;
  __syncthreads();
  for (int off = 128; off > 0; off >>= 1) {
    if (threadIdx.x < off) tmp[threadIdx.x] += tmp[threadIdx.x + off];
    __syncthreads();
  }
  if (threadIdx.x == 0) psum[blockIdx.x] = tmp[0];
}

__global__ __launch_bounds__(256) void scan2_k(int* __restrict__ psum, int P) {
  __shared__ int tmp[256];
  __shared__ int carry_s;
  if (threadIdx.x == 0) carry_s = 0;
  __syncthreads();
  for (int base = 0; base < P; base += 256) {
    int i = base + threadIdx.x;
    int v = (i < P) ? psum[i] : 0;
    tmp[threadIdx.x] = v;
    __syncthreads();
    for (int off = 1; off < 256; off <<= 1) {
      int u = (threadIdx.x >= off) ? tmp[threadIdx.x - off] : 0;
      __syncthreads();
      tmp[threadIdx.x] += u;
      __syncthreads();
    }
    int carry = carry_s;
    if (i < P) psum[i] = carry + tmp[threadIdx.x] - v;
    __syncthreads();
    if (threadIdx.x == 0) carry_s = carry + tmp[255];
    __syncthreads();
  }
}

__global__ __launch_bounds__(256) void scan3_k(const int* __restrict__ icnt,
                                               const int* __restrict__ psum,
                                               int* __restrict__ offs, int M) {
  int base = blockIdx.x * 1024 + threadIdx.x * 4;
  int v[4];
  int s = 0;
#pragma unroll
  for (int j = 0; j < 4; j++) {
    int i = base + j;
    v[j] = (i < M) ? icnt[i] : 0;
    s += v[j];
  }
  __shared__ int tmp[256];
  tmp[threadIdx.x] = s;
  __syncthreads();
  for (int off = 1; off < 256; off <<= 1) {
    int u = (threadIdx.x >= off) ? tmp[threadIdx.x - off] : 0;
    __syncthreads();
    tmp[threadIdx.x] += u;
    __syncthreads();
  }
  int run = psum[blockIdx.x] + tmp[threadIdx.x] - s;
#pragma unroll
  for (int j = 0; j < 4; j++) {
    int i = base + j;
    if (i < M) {
      offs[i] = run;
      run += v[j];
    }
  }
}

__global__ __launch_bounds__(256) void scatter_k(const int* __restrict__ src,
                                                 const int* __restrict__ dst,
                                                 const int* __restrict__ et,
                                                 int* __restrict__ cursor,
                                                 int* __restrict__ csr, int E, int N) {
  int e = blockIdx.x * 256 + threadIdx.x;
  if (e >= E) return;
  int p = atomicAdd(&cursor[et[e] * N + dst[e]], 1);
  csr[p] = src[e];
}

// ====== layer-1 fused: register-walk gather (x rows) + tiled GEMM -> h1 ======
// A = [x | mean_0 | mean_1 | mean_2]  (K=128), weights stacked [root1; W1].
__global__ __launch_bounds__(256) void l1fused_k(
    const float* __restrict__ x,
    const int* __restrict__ offs, const int* __restrict__ icnt, const int* __restrict__ csr,
    const float* __restrict__ root, const float* __restrict__ W, const float* __restrict__ bias,
    float* __restrict__ h1, int N) {
  __shared__ float As[TILE][132];
  __shared__ float Ws[64][64];
  const int t = threadIdx.x;
  const int tx = t & 15, ty = t >> 4;
  const int cg = t & 7, rs = t >> 3;  // col-group (8 x float4), row-slot (32)
  const int n0 = blockIdx.x * TILE;

  // ---- gather phase: thread handles rows {rs, rs+32}, cols [cg*4, cg*4+4) ----
  {
    int nn[2];
#pragma unroll
    for (int u = 0; u < 2; u++) {
      int n = n0 + rs + u * 32;
      nn[u] = (n < N) ? n : N - 1;
      *(float4*)&As[rs + u * 32][cg * 4] = *(const float4*)&x[(size_t)nn[u] * EMB + cg * 4];
    }
    int beg[2][NREL], len[2][NREL];
    int mx = 0;
#pragma unroll
    for (int u = 0; u < 2; u++)
#pragma unroll
      for (int r = 0; r < NREL; r++) {
        int idx = r * N + nn[u];
        beg[u][r] = offs[idx];
        len[u][r] = icnt[idx];
        mx = max(mx, len[u][r]);
      }
    float4 a[2][NREL] = {};
    for (int j = 0; j < mx; j++) {
      int s[2][NREL];
#pragma unroll
      for (int u = 0; u < 2; u++)
#pragma unroll
        for (int r = 0; r < NREL; r++)
          s[u][r] = (j < len[u][r]) ? csr[beg[u][r] + j] : -1;
#pragma unroll
      for (int u = 0; u < 2; u++)
#pragma unroll
        for (int r = 0; r < NREL; r++)
          if (s[u][r] >= 0) {
            float4 v = *(const float4*)&x[(size_t)s[u][r] * EMB + cg * 4];
            a[u][r].x += v.x; a[u][r].y += v.y; a[u][r].z += v.z; a[u][r].w += v.w;
          }
    }
#pragma unroll
    for (int u = 0; u < 2; u++)
#pragma unroll
      for (int r = 0; r < NREL; r++) {
        float inv = 1.f / fmaxf((float)len[u][r], 1.f);
        float4 v = a[u][r];
        v.x *= inv; v.y *= inv; v.z *= inv; v.w *= inv;
        *(float4*)&As[rs + u * 32][32 + r * 32 + cg * 4] = v;
      }
  }
  __syncthreads();

  // ---- GEMM: K = 128 in 2 chunks of 64 ----
  float acc[4][4] = {};
  for (int kc = 0; kc < 2; kc++) {
    if (kc) __syncthreads();
#pragma unroll
    for (int p = 0; p < 4; p++) {
      int row = p * 16 + ty;
      int c4 = tx * 4;
      int wk = kc * 64 + row;
      float4 wv = (wk < EMB) ? *(const float4*)&root[wk * HID + c4]
                             : *(const float4*)&W[(wk - EMB) * HID + c4];
      *(float4*)&Ws[row][c4] = wv;
    }
    __syncthreads();
#pragma unroll 4
    for (int kq = 0; kq < 16; kq++) {
      float4 av[4], wv[4];
#pragma unroll
      for (int m = 0; m < 4; m++) av[m] = *(const float4*)&As[ty * 4 + m][kc * 64 + kq * 4];
#pragma unroll
      for (int i = 0; i < 4; i++) wv[i] = *(const float4*)&Ws[kq * 4 + i][tx * 4];
#pragma unroll
      for (int m = 0; m < 4; m++) {
        const float am[4] = {av[m].x, av[m].y, av[m].z, av[m].w};
#pragma unroll
        for (int i = 0; i < 4; i++) {
          acc[m][0] += am[i] * wv[i].x;
          acc[m][1] += am[i] * wv[i].y;
          acc[m][2] += am[i] * wv[i].z;
          acc[m][3] += am[i] * wv[i].w;
        }
      }
    }
  }
  const int c4 = tx * 4;
  const float4 bv = *(const float4*)&bias[c4];
#pragma unroll
  for (int m = 0; m < 4; m++) {
    int n = n0 + ty * 4 + m;
    if (n < N) {
      float4 o;
      o.x = fmaxf(acc[m][0] + bv.x, 0.f);
      o.y = fmaxf(acc[m][1] + bv.y, 0.f);
      o.z = fmaxf(acc[m][2] + bv.z, 0.f);
      o.w = fmaxf(acc[m][3] + bv.w, 0.f);
      *(float4*)&h1[(size_t)n * HID + c4] = o;
    }
  }
}

// ====== layer-2 fused: register-walk gather (h1 rows) per K-chunk + GEMM + pooled epilogue ======
__global__ __launch_bounds__(256) void l2fused_k(
    const float* __restrict__ h1,
    const int* __restrict__ offs, const int* __restrict__ icnt, const int* __restrict__ csr,
    const float* __restrict__ root, const float* __restrict__ W, const float* __restrict__ bias,
    const float* __restrict__ linW, const int* __restrict__ batch,
    float* __restrict__ gs, float* __restrict__ gc, int N) {
  __shared__ float As[TILE][68];
  __shared__ float Ws[64][64];
  const int t = threadIdx.x;
  const int tx = t & 15, ty = t >> 4;
  const int n0 = blockIdx.x * TILE;
  float acc[4][4] = {};

  for (int kc = 0; kc < 4; kc++) {
    __syncthreads();  // As/Ws safe to overwrite
    const int c4 = tx * 4;
    if (kc == 0) {  // self: copy h1 rows
#pragma unroll
      for (int m = 0; m < 4; m++) {
        int n = n0 + ty * 4 + m;
        if (n >= N) n = N - 1;
        *(float4*)&As[ty * 4 + m][c4] = *(const float4*)&h1[(size_t)n * HID + c4];
      }
    } else {  // relation kc-1: register walk, 4 merged segments per thread
      int r = kc - 1;
      int beg[4], len[4];
      int mx = 0;
#pragma unroll
      for (int m = 0; m < 4; m++) {
        int n = n0 + ty * 4 + m;
        if (n >= N) n = N - 1;
        int idx = r * N + n;
        beg[m] = offs[idx];
        len[m] = icnt[idx];
        mx = max(mx, len[m]);
      }
      float4 a[4] = {};
      for (int j = 0; j < mx; j++) {
        int s[4];
#pragma unroll
        for (int m = 0; m < 4; m++) s[m] = (j < len[m]) ? csr[beg[m] + j] : -1;
#pragma unroll
        for (int m = 0; m < 4; m++)
          if (s[m] >= 0) {
            float4 v = *(const float4*)&h1[(size_t)s[m] * HID + c4];
            a[m].x += v.x; a[m].y += v.y; a[m].z += v.z; a[m].w += v.w;
          }
      }
#pragma unroll
      for (int m = 0; m < 4; m++) {
        float inv = 1.f / fmaxf((float)len[m], 1.f);
        a[m].x *= inv; a[m].y *= inv; a[m].z *= inv; a[m].w *= inv;
        *(float4*)&As[ty * 4 + m][c4] = a[m];
      }
    }
#pragma unroll
    for (int p = 0; p < 4; p++) {
      int row = p * 16 + ty;
      int wk = kc * 64 + row;
      float4 wv = (wk < HID) ? *(const float4*)&root[wk * HID + c4]
                             : *(const float4*)&W[(wk - HID) * HID + c4];
      *(float4*)&Ws[row][c4] = wv;
    }
    __syncthreads();
#pragma unroll 4
    for (int kq = 0; kq < 16; kq++) {
      float4 av[4], wv[4];
#pragma unroll
      for (int m = 0; m < 4; m++) av[m] = *(const float4*)&As[ty * 4 + m][kq * 4];
#pragma unroll
      for (int i = 0; i < 4; i++) wv[i] = *(const float4*)&Ws[kq * 4 + i][tx * 4];
#pragma unroll
      for (int m = 0; m < 4; m++) {
        const float am[4] = {av[m].x, av[m].y, av[m].z, av[m].w};
#pragma unroll
        for (int i = 0; i < 4; i++) {
          acc[m][0] += am[i] * wv[i].x;
          acc[m][1] += am[i] * wv[i].y;
          acc[m][2] += am[i] * wv[i].z;
          acc[m][3] += am[i] * wv[i].w;
        }
      }
    }
  }
  // fused epilogue: bias+relu, project 64->2, reduce across 16 tx lanes, atomics
  const int c4 = tx * 4;
  const float4 bv = *(const float4*)&bias[c4];
  float lw0[4], lw1[4];
#pragma unroll
  for (int c = 0; c < 4; c++) {
    lw0[c] = linW[(c4 + c) * 2 + 0];
    lw1[c] = linW[(c4 + c) * 2 + 1];
  }
#pragma unroll
  for (int m = 0; m < 4; m++) {
    int n = n0 + ty * 4 + m;
    float v0 = fmaxf(acc[m][0] + bv.x, 0.f);
    float v1 = fmaxf(acc[m][1] + bv.y, 0.f);
    float v2 = fmaxf(acc[m][2] + bv.z, 0.f);
    float v3 = fmaxf(acc[m][3] + bv.w, 0.f);
    float t0 = v0 * lw0[0] + v1 * lw0[1] + v2 * lw0[2] + v3 * lw0[3];
    float t1 = v0 * lw1[0] + v1 * lw1[1] + v2 * lw1[2] + v3 * lw1[3];
#pragma unroll
    for (int o = 1; o < 16; o <<= 1) {
      t0 += __shfl_xor(t0, o, 16);
      t1 += __shfl_xor(t1, o, 16);
    }
    if (tx == 0 && n < N) {
      int g = batch[n];
      atomicAdd(&gs[g * 2 + 0], t0);
      atomicAdd(&gs[g * 2 + 1], t1);
      atomicAdd(&gc[g], 1.0f);
    }
  }
}

__global__ __launch_bounds__(256) void final_k(const float* __restrict__ gs,
                                               const float* __restrict__ gc,
                                               const float* __restrict__ linb,
                                               float* __restrict__ out, int G) {
  int i = blockIdx.x * 256 + threadIdx.x;
  if (i >= G * 2) return;
  int g = i >> 1, o = i & 1;
  out[i] = gs[i] / fmaxf(gc[g], 1.0f) + linb[o];
}

extern "C" void kernel_launch(void* const* d_in, const int* in_sizes, int n_in,
                              void* d_out, int out_size, void* d_ws, size_t ws_size,
                              hipStream_t stream) {
  const int* sid = (const int*)d_in[0];
  const int* cid = (const int*)d_in[1];
  const int* pid = (const int*)d_in[2];
  const int* ei = (const int*)d_in[3];
  const int* et = (const int*)d_in[4];
  const int* batch = (const int*)d_in[5];
  const float* se = (const float*)d_in[7];
  const float* ce = (const float*)d_in[8];
  const float* pe = (const float*)d_in[9];
  const float* W1 = (const float*)d_in[10];
  const float* root1 = (const float*)d_in[11];
  const float* b1 = (const float*)d_in[12];
  const float* W2 = (const float*)d_in[13];
  const float* root2 = (const float*)d_in[14];
  const float* b2 = (const float*)d_in[15];
  const float* linW = (const float*)d_in[16];
  const float* linb = (const float*)d_in[17];
  float* out = (float*)d_out;

  const int N = in_sizes[0];
  const int E = in_sizes[4];
  const int G = out_size / 2;
  const int* src = ei;
  const int* dst = ei + E;
  const int M = N * NREL;
  const int P = (M + 1023) / 1024;

  // ---- workspace layout (strictly budgeted) ----
  char* w = (char*)d_ws;
  float* h1 = (float*)w;      w += (size_t)N * HID * sizeof(float);
  float* x = (float*)w;       w += (size_t)N * EMB * sizeof(float);
  float* gs = (float*)w;      w += (size_t)G * 2 * sizeof(float);
  float* gc = (float*)w;      w += (size_t)G * sizeof(float);
  int* icnt = (int*)w;        w += (size_t)M * sizeof(int);
  int* offs = (int*)w;        w += (size_t)M * sizeof(int);
  int* cursor = (int*)w;      w += (size_t)M * sizeof(int);
  int* csr = (int*)w;         w += (size_t)E * sizeof(int);
  int* psum = (int*)w;        w += (size_t)P * sizeof(int);
  if ((size_t)(w - (char*)d_ws) > ws_size) return;  // ws too small: fail loudly, no OOB

  hipMemsetAsync(icnt, 0, (size_t)M * sizeof(int), stream);
  hipMemsetAsync(gs, 0, (size_t)G * 3 * sizeof(float), stream);

  embed_k<<<(N * 8 + 255) / 256, 256, 0, stream>>>(sid, cid, pid, se, ce, pe, x, N);
  hist_k<<<(E + 255) / 256, 256, 0, stream>>>(dst, et, icnt, E, N);
  scan1_k<<<P, 256, 0, stream>>>(icnt, psum, M);
  scan2_k<<<1, 256, 0, stream>>>(psum, P);
  scan3_k<<<P, 256, 0, stream>>>(icnt, psum, offs, M);
  hipMemcpyAsync(cursor, offs, (size_t)M * sizeof(int), hipMemcpyDeviceToDevice, stream);
  scatter_k<<<(E + 255) / 256, 256, 0, stream>>>(src, dst, et, cursor, csr, E, N);

  int blocks = (N + TILE - 1) / TILE;
  l1fused_k<<<blocks, 256, 0, stream>>>(x, offs, icnt, csr, root1, W1, b1, h1, N);
  l2fused_k<<<blocks, 256, 0, stream>>>(h1, offs, icnt, csr, root2, W2, b2, linW, batch, gs, gc,
                                        N);
  final_k<<<(G * 2 + 255) / 256, 256, 0, stream>>>(gs, gc, linb, out, G);
}